// Round 6
// baseline (331.074 us; speedup 1.0000x reference)
//
#include <hip/hip_runtime.h>
#include <hip/hip_bf16.h>
#include <stdint.h>

// MultiHeadAttention fused pipeline for MI355X (gfx950).
// B=4, S=2048, E=768, H=12, D=64.
//  prep_transpose: W fp32 -> Wt bf16 (Wt[n][k] = W[k][n]); also mask->biasF.
//  qkv_gemm (z): C[m=e][n=s] = Wt x X^T. A staged bf16 glds16 (source
//     block-XOR pre-swizzled by (row>>1)&3); B staged FP32 glds16 (source
//     pre-swizzled by row&7), converted bf16 at frag read. ONE barrier
//     per K-tile (prefetch right after barrier -> full-iter slack).
//     Epilogue: z=0 Qh plain [BH][S][64] PRE-SCALED by 0.125*log2e;
//     z=1 Kh d-block XOR-swizzled by s&7; z=2 Vt [BH][64][S], key-block
//     XOR-swizzled by d&7 per 64-key window.
//  attn: double-buffered K/V LDS tiles, ONE barrier per 64-key tile,
//     bias in MFMA acc-init, p=exp2(s) direct, in-register P^T transpose
//     (cvt_pk_bf16 + permlane32/16_swap), rS via ones-row MFMA,
//     s_setprio(1) around MFMA clusters (T5).
//  out_gemm: one-barrier all-glds loop, both operands swizzle-staged.
//
// R1: XCD-aware bijective block swizzle (T1). attn FETCH 107.7->18.5 MB.
// R2/R3: attn LDS/VALU diet. attn 99 -> 76.5 us; conflicts 4.7M -> 0.
// R4 FAILED: reg-staged B prefetch issued right before barrier drain.
// R5: all-glds one-barrier qkv/out + separate xcvt pass. qkv < 76 us but
//   xcvt (~18us) ate the win; qkv still has 3.54M bank-conflict cycles
//   (8-way on 64B-row frag reads: bank=(row*16+quad*4)%32).
// R6: (a) drop xcvt: qkv-B staged fp32 via glds16 (Bsf 32KB), cvt at
//   frag read -- same one-barrier loop, numerics identical. (b) kill
//   GEMM bank conflicts per rule#21: linear LDS dest + inverse-swizzled
//   GLOBAL source + swizzled read. bf16 64B rows: blk ^= (row>>1)&3;
//   fp32 128B rows: blk ^= row&7 (the attn-K pattern, measured 0).
//   (c) attn: setprio(1) around MFMA clusters (T5, +4-7% m191).

typedef __bf16 bf16x8 __attribute__((ext_vector_type(8)));
typedef __bf16 bf16x4 __attribute__((ext_vector_type(4)));
typedef float floatx4 __attribute__((ext_vector_type(4)));

#define MFMA_BF16(a, b, c) __builtin_amdgcn_mfma_f32_16x16x32_bf16(a, b, c, 0, 0, 0)

// MFMA 16x16x32 layouts (verified, learn_hip m89/m91):
//   A frag: A[m = lane&15][k = (lane>>4)*8 + j]
//   B frag: B[k = (lane>>4)*8 + j][n = lane&15]   (read from [n][k] storage)
//   C/D  : C[m = (lane>>4)*4 + r][n = lane&15]

__device__ __forceinline__ void glds16(const void* g, void* l) {
  __builtin_amdgcn_global_load_lds(
      (const __attribute__((address_space(1))) unsigned int*)g,
      (__attribute__((address_space(3))) unsigned int*)l, 16, 0, 0);
}

#if __has_builtin(__builtin_amdgcn_permlane32_swap)
__device__ __forceinline__ void perm32_swap(unsigned int& a, unsigned int& b) {
  auto r = __builtin_amdgcn_permlane32_swap(a, b, false, false);
  a = r[0];
  b = r[1];
}
#else
__device__ __forceinline__ void perm32_swap(unsigned int& a, unsigned int& b) {
  asm("v_permlane32_swap_b32 %0, %1" : "+v"(a), "+v"(b));
}
#endif

#if __has_builtin(__builtin_amdgcn_permlane16_swap)
__device__ __forceinline__ void perm16_swap(unsigned int& a, unsigned int& b) {
  auto r = __builtin_amdgcn_permlane16_swap(a, b, false, false);
  a = r[0];
  b = r[1];
}
#else
__device__ __forceinline__ void perm16_swap(unsigned int& a, unsigned int& b) {
  asm("v_permlane16_swap_b32 %0, %1" : "+v"(a), "+v"(b));
}
#endif

// ---------------------------------------------------------------------------
// prep: transpose+convert weights; 8 of the z==3 blocks also build the
// f32 mask-bias table (mask ? 0 : -1e5). grid (24, 24, 4), block 256.
// ---------------------------------------------------------------------------
__global__ __launch_bounds__(256) void prep_transpose(
    const float* __restrict__ W0, const float* __restrict__ W1,
    const float* __restrict__ W2, const float* __restrict__ W3,
    __bf16* __restrict__ T0, __bf16* __restrict__ T1,
    __bf16* __restrict__ T2, __bf16* __restrict__ T3,
    const int* __restrict__ mask, float* __restrict__ biasF) {
  const int z = blockIdx.z;
  const float* W = (z == 0) ? W0 : (z == 1) ? W1 : (z == 2) ? W2 : W3;
  __bf16* T = (z == 0) ? T0 : (z == 1) ? T1 : (z == 2) ? T2 : T3;
  __shared__ float t[32][33];
  const int tx = threadIdx.x & 31, ty = threadIdx.x >> 5;
  const int kb = blockIdx.x * 32, nb = blockIdx.y * 32;
#pragma unroll
  for (int j = 0; j < 4; ++j)
    t[ty + j * 8][tx] = W[(size_t)(kb + ty + j * 8) * 768 + nb + tx];
  if (z == 3 && blockIdx.y == 0 && blockIdx.x < 8) {
    const int idx = blockIdx.x * 1024 + threadIdx.x * 4;
    const int4 m4 = *(const int4*)&mask[idx];
    float4 f4;
    f4.x = m4.x ? 0.0f : -1e5f;
    f4.y = m4.y ? 0.0f : -1e5f;
    f4.z = m4.z ? 0.0f : -1e5f;
    f4.w = m4.w ? 0.0f : -1e5f;
    *(float4*)&biasF[idx] = f4;
  }
  __syncthreads();
#pragma unroll
  for (int j = 0; j < 4; ++j)
    T[(size_t)(nb + ty + j * 8) * 768 + kb + tx] = (__bf16)t[tx][ty + j * 8];
}

// ---------------------------------------------------------------------------
// QKV projection GEMM. grid (6, 64, 3), block 256. Tile 128x128, BK=32.
// A bf16 glds (swz (row>>1)&3); B fp32 glds (swz row&7), cvt at frag read.
// One barrier per K-tile. XCD swizzle cpx=144.
// ---------------------------------------------------------------------------
__global__ __launch_bounds__(256) void qkv_gemm(
    const __bf16* __restrict__ Wtq, const __bf16* __restrict__ Wtk,
    const __bf16* __restrict__ Wtv, const float* __restrict__ Xq,
    const float* __restrict__ Xk, const float* __restrict__ Xv,
    const float* __restrict__ bq, const float* __restrict__ bk,
    const float* __restrict__ bv, __bf16* __restrict__ Qh,
    __bf16* __restrict__ Kh, __bf16* __restrict__ Vt) {
  __shared__ __align__(16) __bf16 As[2][128 * 32];   // 16 KB
  __shared__ __align__(16) float Bsf[2][128 * 32];   // 32 KB
  const int gid = blockIdx.x + 6 * blockIdx.y + 384 * blockIdx.z;
  const int swz = (gid & 7) * 144 + (gid >> 3);
  const int z = swz / 384;
  const int rem = swz - z * 384;
  const int by = rem / 6;
  const int bx = rem - by * 6;

  const __bf16* Aop = (z == 0) ? Wtq : (z == 1) ? Wtk : Wtv;
  const float* Bop = (z == 0) ? Xq : (z == 1) ? Xk : Xv;
  const float* bias = (z == 0) ? bq : (z == 1) ? bk : bv;
  __bf16* Dst = (z == 0) ? Qh : (z == 1) ? Kh : Vt;
  const int m0 = bx * 128, n0 = by * 128;

  const int tid = threadIdx.x, lane = tid & 63, w = tid >> 6;
  const int quad = lane >> 4, l16 = lane & 15;
  const int wm = (w >> 1) * 64, wn = (w & 1) * 64;

  // A staging (64B rows, 16 rows/inst): row = w*32 + j*16 + (lane>>2);
  // source block pre-swizzled by (row>>1)&3 = (lane>>3)&3.
  const int garow = w * 32 + (lane >> 2);
  const int gacol = (((lane & 3) ^ ((lane >> 3) & 3)) * 8);
  const __bf16* gA = Aop + (size_t)(m0 + garow) * 768 + gacol;  // tile: +it*32
  // B staging fp32 (128B rows, 8 rows/inst): row = w*32 + j*8 + (lane>>3);
  // source block pre-swizzled by row&7 = lane>>3... (j*8 drops out mod 8).
  const int gbrow = w * 32 + (lane >> 3);
  const int gbcol = (((lane & 7) ^ ((lane >> 3) & 7)) * 4);
  const float* gB = Bop + (size_t)(n0 + gbrow) * 768 + gbcol;   // tile: +it*32

  // swizzled frag-read columns
  const int colA = (quad ^ ((l16 >> 1) & 3)) * 8;   // bf16 elems
  const int blkB = (2 * quad) ^ (l16 & 7);          // f32 4-elem block idx

  floatx4 acc[4][4] = {};

  // prologue: stage tile 0
  glds16(gA, &As[0][w * 1024]);
  glds16(gA + (size_t)16 * 768, &As[0][w * 1024 + 512]);
#pragma unroll
  for (int j = 0; j < 4; ++j)
    glds16(gB + (size_t)(8 * j) * 768, &Bsf[0][w * 1024 + j * 256]);

#pragma unroll 2
  for (int it = 0; it < 24; ++it) {
    const int c = it & 1;
    __syncthreads();  // drains tile-it staging (issued a full iter ago)
    if (it < 23) {
      glds16(gA + (size_t)(it + 1) * 32, &As[c ^ 1][w * 1024]);
      glds16(gA + (size_t)(it + 1) * 32 + (size_t)16 * 768,
             &As[c ^ 1][w * 1024 + 512]);
#pragma unroll
      for (int j = 0; j < 4; ++j)
        glds16(gB + (size_t)(8 * j) * 768 + (it + 1) * 32,
               &Bsf[c ^ 1][w * 1024 + j * 256]);
    }
    bf16x8 af[4], bfr[4];
#pragma unroll
    for (int t = 0; t < 4; ++t) {
      af[t] = *(const bf16x8*)&As[c][(wm + t * 16 + l16) * 32 + colA];
      const int r = (wn + t * 16 + l16) * 32;
      const float4 fa = *(const float4*)&Bsf[c][r + blkB * 4];
      const float4 fb = *(const float4*)&Bsf[c][r + (blkB ^ 1) * 4];
      bf16x8 bb;
      bb[0] = (__bf16)fa.x; bb[1] = (__bf16)fa.y;
      bb[2] = (__bf16)fa.z; bb[3] = (__bf16)fa.w;
      bb[4] = (__bf16)fb.x; bb[5] = (__bf16)fb.y;
      bb[6] = (__bf16)fb.z; bb[7] = (__bf16)fb.w;
      bfr[t] = bb;
    }
#pragma unroll
    for (int mt = 0; mt < 4; ++mt)
#pragma unroll
      for (int nt = 0; nt < 4; ++nt)
        acc[mt][nt] = MFMA_BF16(af[mt], bfr[nt], acc[mt][nt]);
  }

  // epilogue; z==0 pre-scales Q by 0.125*log2e (softmax scale fold)
  const float qs = (z == 0) ? 0.18033688011112042f : 1.0f;
#pragma unroll
  for (int mt = 0; mt < 4; ++mt) {
    const int e = m0 + wm + mt * 16 + quad * 4;
    const float4 b4 = *(const float4*)&bias[e];
    const int h = e >> 6, d = e & 63;
#pragma unroll
    for (int nt = 0; nt < 4; ++nt) {
      const int s = n0 + wn + nt * 16 + l16;
      const int bb = s >> 11, sr = s & 2047;
      const float v0 = (acc[mt][nt][0] + b4.x) * qs;
      const float v1 = (acc[mt][nt][1] + b4.y) * qs;
      const float v2 = (acc[mt][nt][2] + b4.z) * qs;
      const float v3 = (acc[mt][nt][3] + b4.w) * qs;
      if (z < 2) {
        bf16x4 pv;
        pv[0] = (__bf16)v0; pv[1] = (__bf16)v1; pv[2] = (__bf16)v2; pv[3] = (__bf16)v3;
        const int col = (z == 0) ? d : ((((d >> 3) ^ (sr & 7)) << 3) | (d & 7));
        *(bf16x4*)&Dst[((size_t)(bb * 12 + h) * 2048 + sr) * 64 + col] = pv;
      } else {
        const size_t rowbase = ((size_t)(bb * 12 + h) * 64 + d) * 2048;
        const int shi = sr & ~63, sblk = (sr >> 3) & 7, soff = sr & 7;
        Dst[rowbase + 0 * 2048 + shi + (((sblk ^ ((d + 0) & 7))) << 3) + soff] = (__bf16)v0;
        Dst[rowbase + 1 * 2048 + shi + (((sblk ^ ((d + 1) & 7))) << 3) + soff] = (__bf16)v1;
        Dst[rowbase + 2 * 2048 + shi + (((sblk ^ ((d + 2) & 7))) << 3) + soff] = (__bf16)v2;
        Dst[rowbase + 3 * 2048 + shi + (((sblk ^ ((d + 3) & 7))) << 3) + soff] = (__bf16)v3;
      }
    }
  }
}

// ---------------------------------------------------------------------------
// Output projection GEMM. grid (6, 64), block 256. All-glds, one barrier,
// both operands source-swizzled by (row>>1)&3. XCD swizzle cpx=48.
// ---------------------------------------------------------------------------
__global__ __launch_bounds__(256) void out_gemm(const __bf16* __restrict__ Wto,
                                                const __bf16* __restrict__ Ctx,
                                                const float* __restrict__ bo,
                                                float* __restrict__ Out) {
  __shared__ __align__(16) __bf16 As[2][128 * 32];
  __shared__ __align__(16) __bf16 Bs[2][128 * 32];
  const int gid = blockIdx.x + 6 * blockIdx.y;
  const int swz = (gid & 7) * 48 + (gid >> 3);
  const int by = swz / 6;
  const int bx = swz - by * 6;
  const int m0 = bx * 128, n0 = by * 128;
  const int tid = threadIdx.x, lane = tid & 63, w = tid >> 6;
  const int quad = lane >> 4, l16 = lane & 15;
  const int wm = (w >> 1) * 64, wn = (w & 1) * 64;

  const int grow = w * 32 + (lane >> 2);
  const int gcol = (((lane & 3) ^ ((lane >> 3) & 3)) * 8);
  const __bf16* gA = Wto + (size_t)(m0 + grow) * 768 + gcol;
  const __bf16* gB = Ctx + (size_t)(n0 + grow) * 768 + gcol;
  const int colA = (quad ^ ((l16 >> 1) & 3)) * 8;

  floatx4 acc[4][4] = {};

  glds16(gA, &As[0][w * 1024]);
  glds16(gA + (size_t)16 * 768, &As[0][w * 1024 + 512]);
  glds16(gB, &Bs[0][w * 1024]);
  glds16(gB + (size_t)16 * 768, &Bs[0][w * 1024 + 512]);

#pragma unroll 2
  for (int it = 0; it < 24; ++it) {
    const int c = it & 1;
    __syncthreads();
    if (it < 23) {
      glds16(gA + (size_t)(it + 1) * 32, &As[c ^ 1][w * 1024]);
      glds16(gA + (size_t)(it + 1) * 32 + (size_t)16 * 768,
             &As[c ^ 1][w * 1024 + 512]);
      glds16(gB + (size_t)(it + 1) * 32, &Bs[c ^ 1][w * 1024]);
      glds16(gB + (size_t)(it + 1) * 32 + (size_t)16 * 768,
             &Bs[c ^ 1][w * 1024 + 512]);
    }
    bf16x8 af[4], bfr[4];
#pragma unroll
    for (int t = 0; t < 4; ++t) {
      af[t] = *(const bf16x8*)&As[c][(wm + t * 16 + l16) * 32 + colA];
      bfr[t] = *(const bf16x8*)&Bs[c][(wn + t * 16 + l16) * 32 + colA];
    }
#pragma unroll
    for (int mt = 0; mt < 4; ++mt)
#pragma unroll
      for (int nt = 0; nt < 4; ++nt)
        acc[mt][nt] = MFMA_BF16(af[mt], bfr[nt], acc[mt][nt]);
  }

#pragma unroll
  for (int mt = 0; mt < 4; ++mt) {
    const int e = m0 + wm + mt * 16 + quad * 4;
    const float4 b4 = *(const float4*)&bo[e];
#pragma unroll
    for (int nt = 0; nt < 4; ++nt) {
      const int s = n0 + wn + nt * 16 + l16;
      float4 r;
      r.x = acc[mt][nt][0] + b4.x;
      r.y = acc[mt][nt][1] + b4.y;
      r.z = acc[mt][nt][2] + b4.z;
      r.w = acc[mt][nt][3] + b4.w;
      *(float4*)&Out[(size_t)s * 768 + e] = r;
    }
  }
}

// ---------------------------------------------------------------------------
// Flash attention. grid (16, 48), block 256 (4 waves). Double-buffered K/V,
// one barrier/iter; bias in QK^T acc-init; exp2 direct; in-register P^T
// transpose; rS via ones-MFMA; setprio around MFMA clusters (T5).
// XCD swizzle: cpx=96; K/V panels L2-resident per XCD.
// ---------------------------------------------------------------------------
__global__ __launch_bounds__(256) void attn_kernel(
    const __bf16* __restrict__ Qh, const __bf16* __restrict__ Kh,
    const __bf16* __restrict__ Vt, const float* __restrict__ biasF,
    __bf16* __restrict__ ctx) {
  const int lid = blockIdx.x + 16 * blockIdx.y;
  const int swz = (lid & 7) * 96 + (lid >> 3);
  const int qx = swz & 15, bh = swz >> 4;
  const int b = bh / 12, h = bh - b * 12;
  const int tid = threadIdx.x, lane = tid & 63, w = tid >> 6;
  const int quad = lane >> 4, l16 = lane & 15;
  const int q0 = qx * 128 + w * 32;

  __shared__ __align__(16) __bf16 Ks[2][64 * 64];     // [buf][key][d-swz]
  __shared__ __align__(16) __bf16 Vs[2][64 * 64];     // [buf][d][key-swz]

  const __bf16* Qbase = Qh + (size_t)bh * 2048 * 64;
  const __bf16* Kbase = Kh + (size_t)bh * 2048 * 64;
  const __bf16* Vbase = Vt + (size_t)bh * 64 * 2048;
  const float* biasB = biasF + b * 2048;

  // Q B-frags (plain layout, pre-scaled): B[k=d][n=q] from Qh[q][d]
  bf16x8 bqf[2][2];
#pragma unroll
  for (int qt = 0; qt < 2; ++qt)
#pragma unroll
    for (int c = 0; c < 2; ++c)
      bqf[qt][c] =
          *(const bf16x8*)&Qbase[(size_t)(q0 + qt * 16 + l16) * 64 + c * 32 + quad * 8];

  // staging (128 B rows): chunk c covers rows c*8 + (lane>>3), col (lane&7)*8
  const int r0 = (w * 2) * 8 + (lane >> 3);
  const int r1 = (w * 2 + 1) * 8 + (lane >> 3);
  const int scol = (lane & 7) * 8;
  const int d0 = (w * 2) * 512;
  const int d1 = (w * 2 + 1) * 512;
  const int col0 = (quad ^ (l16 & 7)) * 8;

  // prologue: stage tile 0 into buffer 0
  glds16(&Kbase[(size_t)r0 * 64 + scol], &Ks[0][d0]);
  glds16(&Kbase[(size_t)r1 * 64 + scol], &Ks[0][d1]);
  glds16(&Vbase[(size_t)r0 * 2048 + scol], &Vs[0][d0]);
  glds16(&Vbase[(size_t)r1 * 2048 + scol], &Vs[0][d1]);

  floatx4 o[4][2] = {};   // O^T accs: [d-tile][q-tile]
  floatx4 os[2] = {};     // rS accs via ones-MFMA
  bf16x8 ones8;
#pragma unroll
  for (int j = 0; j < 8; ++j) ones8[j] = (__bf16)1.0f;

  for (int it = 0; it < 32; ++it) {
    const int kt = it * 64;
    const int cur = it & 1;
    const int nxt = cur ^ 1;
    const int nkt = (kt + 64) & 2047;  // wrap: last-iter prefetch is harmless

    __syncthreads();  // drains tile-`it` staging (in flight since iter it-1)

    // ---- prefetch tile it+1 into the other buffer (overlaps compute below)
    glds16(&Kbase[(size_t)(nkt + r0) * 64 + scol], &Ks[nxt][d0]);
    glds16(&Kbase[(size_t)(nkt + r1) * 64 + scol], &Ks[nxt][d1]);
    glds16(&Vbase[(size_t)r0 * 2048 + nkt + scol], &Vs[nxt][d0]);
    glds16(&Vbase[(size_t)r1 * 2048 + nkt + scol], &Vs[nxt][d1]);

    // ---- scores S^T with bias in acc-init: 4 key-tiles x 2 q-tiles
    floatx4 sc[4][2];
    __builtin_amdgcn_s_setprio(1);
#pragma unroll
    for (int t = 0; t < 4; ++t) {
      const float4 bf4 = *(const float4*)&biasB[kt + t * 16 + quad * 4];
      bf16x8 ak0 = *(const bf16x8*)&Ks[cur][(t * 16 + l16) * 64 + col0];
      bf16x8 ak1 = *(const bf16x8*)&Ks[cur][(t * 16 + l16) * 64 + (col0 ^ 32)];
#pragma unroll
      for (int qt = 0; qt < 2; ++qt) {
        floatx4 zz;
        zz[0] = bf4.x; zz[1] = bf4.y; zz[2] = bf4.z; zz[3] = bf4.w;
        zz = MFMA_BF16(ak0, bqf[qt][0], zz);
        zz = MFMA_BF16(ak1, bqf[qt][1], zz);
        sc[t][qt] = zz;
      }
    }
    __builtin_amdgcn_s_setprio(0);
    // ---- p = exp2(s); pack pairs to bf16 words (keys +0,1 / +2,3 per word)
    unsigned int u[4][2][2];
#pragma unroll
    for (int t = 0; t < 4; ++t)
#pragma unroll
      for (int qt = 0; qt < 2; ++qt) {
        const float e0 = __builtin_amdgcn_exp2f(sc[t][qt][0]);
        const float e1 = __builtin_amdgcn_exp2f(sc[t][qt][1]);
        const float e2 = __builtin_amdgcn_exp2f(sc[t][qt][2]);
        const float e3 = __builtin_amdgcn_exp2f(sc[t][qt][3]);
        asm("v_cvt_pk_bf16_f32 %0, %1, %2" : "=v"(u[t][qt][0]) : "v"(e0), "v"(e1));
        asm("v_cvt_pk_bf16_f32 %0, %1, %2" : "=v"(u[t][qt][1]) : "v"(e2), "v"(e3));
      }
    // ---- in-register P^T -> B-frags; O^T += V^T @ P^T; rS += ones @ P^T
#pragma unroll
    for (int c = 0; c < 2; ++c) {
      bf16x8 bp[2];
#pragma unroll
      for (int qt = 0; qt < 2; ++qt) {
        unsigned int w0 = u[2 * c][qt][0], w1 = u[2 * c][qt][1];
        unsigned int w2 = u[2 * c + 1][qt][0], w3 = u[2 * c + 1][qt][1];
        perm32_swap(w0, w2);
        perm32_swap(w1, w3);
        perm16_swap(w0, w2);
        perm16_swap(w1, w3);
        union { unsigned int wd[4]; bf16x8 v; } ub;
        ub.wd[0] = w0; ub.wd[1] = w1; ub.wd[2] = w2; ub.wd[3] = w3;
        bp[qt] = ub.v;
      }
      __builtin_amdgcn_s_setprio(1);
      os[0] = MFMA_BF16(ones8, bp[0], os[0]);
      os[1] = MFMA_BF16(ones8, bp[1], os[1]);
#pragma unroll
      for (int dt = 0; dt < 4; ++dt) {
        bf16x8 av = *(const bf16x8*)&Vs[cur][(dt * 16 + l16) * 64 + (col0 ^ (c * 32))];
#pragma unroll
        for (int qt = 0; qt < 2; ++qt) o[dt][qt] = MFMA_BF16(av, bp[qt], o[dt][qt]);
      }
      __builtin_amdgcn_s_setprio(0);
    }
  }

  // ---- normalize + write ctx (every lane holds its q's sum in os[qt][0])
  float inv[2];
  inv[0] = 1.0f / os[0][0];
  inv[1] = 1.0f / os[1][0];
#pragma unroll
  for (int dt = 0; dt < 4; ++dt)
#pragma unroll
    for (int qt = 0; qt < 2; ++qt) {
      const int q = q0 + qt * 16 + l16;
      const int d = h * 64 + dt * 16 + quad * 4;
      bf16x4 pv;
      pv[0] = (__bf16)(o[dt][qt][0] * inv[qt]);
      pv[1] = (__bf16)(o[dt][qt][1] * inv[qt]);
      pv[2] = (__bf16)(o[dt][qt][2] * inv[qt]);
      pv[3] = (__bf16)(o[dt][qt][3] * inv[qt]);
      *(bf16x4*)&ctx[(size_t)(b * 2048 + q) * 768 + d] = pv;
    }
}

// ---------------------------------------------------------------------------
extern "C" void kernel_launch(void* const* d_in, const int* in_sizes, int n_in,
                              void* d_out, int out_size, void* d_ws, size_t ws_size,
                              hipStream_t stream) {
  const float* q = (const float*)d_in[0];
  const float* k = (const float*)d_in[1];
  const float* v = (const float*)d_in[2];
  const int* mask = (const int*)d_in[3];
  const float* Wq = (const float*)d_in[4];
  const float* bq = (const float*)d_in[5];
  const float* Wk = (const float*)d_in[6];
  const float* bk = (const float*)d_in[7];
  const float* Wv = (const float*)d_in[8];
  const float* bv = (const float*)d_in[9];
  const float* Wo = (const float*)d_in[10];
  const float* bo = (const float*)d_in[11];
  float* out = (float*)d_out;

  char* ws = (char*)d_ws;
  const size_t SZ = (size_t)8192 * 768 * 2;   // 12.58 MB
  const size_t WSZ = (size_t)768 * 768 * 2;   // 1.18 MB
  __bf16* Qh = (__bf16*)(ws);
  __bf16* Kh = (__bf16*)(ws + SZ);
  __bf16* Vt = (__bf16*)(ws + 2 * SZ);
  __bf16* ctx = (__bf16*)(ws + 3 * SZ);
  __bf16* Wtq = (__bf16*)(ws + 4 * SZ);
  __bf16* Wtk = (__bf16*)(ws + 4 * SZ + WSZ);
  __bf16* Wtv = (__bf16*)(ws + 4 * SZ + 2 * WSZ);
  __bf16* Wto = (__bf16*)(ws + 4 * SZ + 3 * WSZ);
  float* biasF = (float*)(ws + 4 * SZ + 4 * WSZ);  // 4*2048 f32 = 32 KB

  prep_transpose<<<dim3(24, 24, 4), 256, 0, stream>>>(Wq, Wk, Wv, Wo, Wtq, Wtk,
                                                      Wtv, Wto, mask, biasF);
  qkv_gemm<<<dim3(6, 64, 3), 256, 0, stream>>>(Wtq, Wtk, Wtv, q, k, v, bq, bk, bv,
                                               Qh, Kh, Vt);
  attn_kernel<<<dim3(16, 48), 256, 0, stream>>>(Qh, Kh, Vt, biasF, ctx);
  out_gemm<<<dim3(6, 64), 256, 0, stream>>>(Wto, ctx, bo, out);
}

// Round 7
// 315.035 us; speedup vs baseline: 1.0509x; 1.0509x over previous
//
#include <hip/hip_runtime.h>
#include <hip/hip_bf16.h>
#include <stdint.h>

// MultiHeadAttention fused pipeline for MI355X (gfx950).
// B=4, S=2048, E=768, H=12, D=64.
//  prep_transpose: W fp32 -> Wt bf16 (Wt[n][k] = W[k][n]); also mask->biasF.
//  qkv_gemm (z): C[m=e][n=s] = Wt (bf16 glds) x X^T (fp32 reg-staged,
//     inline cvt). ONE barrier per K-tile; B loads issued early and
//     consumed SAME-iter (never outstanding across a barrier).
//     Epilogue: z=0 Qh plain [BH][S][64] PRE-SCALED by 0.125*log2e;
//     z=1 Kh d-block XOR-swizzled by s&7; z=2 Vt [BH][64][S], key-block
//     XOR-swizzled by d&7 per 64-key window.
//  attn: double-buffered K/V LDS tiles, ONE barrier per 64-key tile,
//     bias in MFMA acc-init, p=exp2(s) direct, in-register P^T transpose
//     (cvt_pk_bf16 + permlane32/16_swap), rS via ones-row MFMA, setprio.
//  out_gemm: one-barrier all-glds loop (R5-exact).
//
// R1: XCD-aware bijective block swizzle (T1). attn FETCH 107.7->18.5 MB.
// R2/R3: attn LDS/VALU diet. attn 99 -> 76.5 us; attn conflicts 4.7M -> 0.
// R4 FAILED: B reg-loads crossed the barrier while outstanding (vmcnt(0)
//   drain with zero slack every iter).
// R5: all-glds qkv + xcvt pass: qkv <76 but xcvt ~18us ate the win.
// R6 FAILED: fp32-B-in-LDS: 48KB LDS (occ 16.9%), 2x B staging bytes,
//   64 cvts on frag path -> qkv 122us. ALSO: qkv bank-conflict counter
//   (3538944) is bit-identical across all frag-read swizzle schemes ->
//   that counter is inert to swizzles here; stop chasing it.
// R7: one-barrier reg-staged-B with correct T14 schedule: per iter
//   barrier -> issue glds A(it+1) -> issue B(it+1) fp32 loads -> frag
//   ds_reads(it) -> 16 MFMA (covers B latency) -> cvt+ds_write Bs[^1].
//   f consumed before the next barrier; only glds-A (full-iter slack)
//   is ever outstanding at a barrier. No xcvt, LDS 32KB.

typedef __bf16 bf16x8 __attribute__((ext_vector_type(8)));
typedef __bf16 bf16x4 __attribute__((ext_vector_type(4)));
typedef float floatx4 __attribute__((ext_vector_type(4)));

#define MFMA_BF16(a, b, c) __builtin_amdgcn_mfma_f32_16x16x32_bf16(a, b, c, 0, 0, 0)

// MFMA 16x16x32 layouts (verified, learn_hip m89/m91):
//   A frag: A[m = lane&15][k = (lane>>4)*8 + j]
//   B frag: B[k = (lane>>4)*8 + j][n = lane&15]   (read from [n][k] storage)
//   C/D  : C[m = (lane>>4)*4 + r][n = lane&15]

__device__ __forceinline__ void glds16(const void* g, void* l) {
  __builtin_amdgcn_global_load_lds(
      (const __attribute__((address_space(1))) unsigned int*)g,
      (__attribute__((address_space(3))) unsigned int*)l, 16, 0, 0);
}

#if __has_builtin(__builtin_amdgcn_permlane32_swap)
__device__ __forceinline__ void perm32_swap(unsigned int& a, unsigned int& b) {
  auto r = __builtin_amdgcn_permlane32_swap(a, b, false, false);
  a = r[0];
  b = r[1];
}
#else
__device__ __forceinline__ void perm32_swap(unsigned int& a, unsigned int& b) {
  asm("v_permlane32_swap_b32 %0, %1" : "+v"(a), "+v"(b));
}
#endif

#if __has_builtin(__builtin_amdgcn_permlane16_swap)
__device__ __forceinline__ void perm16_swap(unsigned int& a, unsigned int& b) {
  auto r = __builtin_amdgcn_permlane16_swap(a, b, false, false);
  a = r[0];
  b = r[1];
}
#else
__device__ __forceinline__ void perm16_swap(unsigned int& a, unsigned int& b) {
  asm("v_permlane16_swap_b32 %0, %1" : "+v"(a), "+v"(b));
}
#endif

// ---------------------------------------------------------------------------
// prep: transpose+convert weights; 8 of the z==3 blocks also build the
// f32 mask-bias table (mask ? 0 : -1e5). grid (24, 24, 4), block 256.
// ---------------------------------------------------------------------------
__global__ __launch_bounds__(256) void prep_transpose(
    const float* __restrict__ W0, const float* __restrict__ W1,
    const float* __restrict__ W2, const float* __restrict__ W3,
    __bf16* __restrict__ T0, __bf16* __restrict__ T1,
    __bf16* __restrict__ T2, __bf16* __restrict__ T3,
    const int* __restrict__ mask, float* __restrict__ biasF) {
  const int z = blockIdx.z;
  const float* W = (z == 0) ? W0 : (z == 1) ? W1 : (z == 2) ? W2 : W3;
  __bf16* T = (z == 0) ? T0 : (z == 1) ? T1 : (z == 2) ? T2 : T3;
  __shared__ float t[32][33];
  const int tx = threadIdx.x & 31, ty = threadIdx.x >> 5;
  const int kb = blockIdx.x * 32, nb = blockIdx.y * 32;
#pragma unroll
  for (int j = 0; j < 4; ++j)
    t[ty + j * 8][tx] = W[(size_t)(kb + ty + j * 8) * 768 + nb + tx];
  if (z == 3 && blockIdx.y == 0 && blockIdx.x < 8) {
    const int idx = blockIdx.x * 1024 + threadIdx.x * 4;
    const int4 m4 = *(const int4*)&mask[idx];
    float4 f4;
    f4.x = m4.x ? 0.0f : -1e5f;
    f4.y = m4.y ? 0.0f : -1e5f;
    f4.z = m4.z ? 0.0f : -1e5f;
    f4.w = m4.w ? 0.0f : -1e5f;
    *(float4*)&biasF[idx] = f4;
  }
  __syncthreads();
#pragma unroll
  for (int j = 0; j < 4; ++j)
    T[(size_t)(nb + ty + j * 8) * 768 + kb + tx] = (__bf16)t[tx][ty + j * 8];
}

// ---------------------------------------------------------------------------
// QKV projection GEMM. grid (6, 64, 3), block 256. Tile 128x128, BK=32.
// One barrier/iter; A bf16 glds; B fp32 reg-staged same-iter (R7).
// XCD swizzle cpx=144.
// ---------------------------------------------------------------------------
__global__ __launch_bounds__(256) void qkv_gemm(
    const __bf16* __restrict__ Wtq, const __bf16* __restrict__ Wtk,
    const __bf16* __restrict__ Wtv, const float* __restrict__ Xq,
    const float* __restrict__ Xk, const float* __restrict__ Xv,
    const float* __restrict__ bq, const float* __restrict__ bk,
    const float* __restrict__ bv, __bf16* __restrict__ Qh,
    __bf16* __restrict__ Kh, __bf16* __restrict__ Vt) {
  __shared__ __align__(16) __bf16 As[2][128 * 32];   // 8 KB each
  __shared__ __align__(16) __bf16 Bs[2][128 * 32];
  const int gid = blockIdx.x + 6 * blockIdx.y + 384 * blockIdx.z;
  const int swz = (gid & 7) * 144 + (gid >> 3);
  const int z = swz / 384;
  const int rem = swz - z * 384;
  const int by = rem / 6;
  const int bx = rem - by * 6;

  const __bf16* Aop = (z == 0) ? Wtq : (z == 1) ? Wtk : Wtv;
  const float* Bop = (z == 0) ? Xq : (z == 1) ? Xk : Xv;
  const float* bias = (z == 0) ? bq : (z == 1) ? bk : bv;
  __bf16* Dst = (z == 0) ? Qh : (z == 1) ? Kh : Vt;
  const int m0 = bx * 128, n0 = by * 128;

  const int tid = threadIdx.x, lane = tid & 63, w = tid >> 6;
  const int quad = lane >> 4, l16 = lane & 15;
  const int wm = (w >> 1) * 64, wn = (w & 1) * 64;

  // A staging (glds, 64B rows): wave w insts j=0,1 -> rows w*32+j*16+(lane>>2)
  const int garow = w * 32 + (lane >> 2);
  const int gacol = (lane & 3) * 8;
  const __bf16* gA = Aop + (size_t)(m0 + garow) * 768 + gacol;  // tile: +it*32
  // B reg staging: pass j covers rows (tid>>3)+32j, col (tid&7)*4
  const int brow = tid >> 3, bcol = (tid & 7) * 4;
  const float* gB = Bop + (size_t)(n0 + brow) * 768 + bcol;     // tile: +it*32

  floatx4 acc[4][4] = {};
  float4 f[4];

  // ---- prologue: stage tile 0 (A via glds; B via regs -> Bs[0])
  glds16(gA, &As[0][w * 1024]);
  glds16(gA + (size_t)16 * 768, &As[0][w * 1024 + 512]);
#pragma unroll
  for (int j = 0; j < 4; ++j) f[j] = *(const float4*)&gB[(size_t)(32 * j) * 768];
#pragma unroll
  for (int j = 0; j < 4; ++j) {
    bf16x4 pv;
    pv[0] = (__bf16)f[j].x; pv[1] = (__bf16)f[j].y;
    pv[2] = (__bf16)f[j].z; pv[3] = (__bf16)f[j].w;
    *(bf16x4*)&Bs[0][(brow + 32 * j) * 32 + bcol] = pv;
  }

#pragma unroll 2
  for (int it = 0; it < 24; ++it) {
    const int c = it & 1;
    __syncthreads();  // drains glds A(it) + Bs[c] ds_writes (both 1 iter old)
    if (it < 23) {
      // issue next A tile (drained at next barrier, full-iter slack)
      glds16(gA + (size_t)(it + 1) * 32, &As[c ^ 1][w * 1024]);
      glds16(gA + (size_t)(it + 1) * 32 + (size_t)16 * 768,
             &As[c ^ 1][w * 1024 + 512]);
      // issue B(it+1) fp32 loads NOW; consumed after the MFMA block below
#pragma unroll
      for (int j = 0; j < 4; ++j)
        f[j] = *(const float4*)&gB[(size_t)(32 * j) * 768 + (it + 1) * 32];
    }
    bf16x8 af[4], bfr[4];
#pragma unroll
    for (int t = 0; t < 4; ++t) {
      af[t] = *(const bf16x8*)&As[c][(wm + t * 16 + l16) * 32 + quad * 8];
      bfr[t] = *(const bf16x8*)&Bs[c][(wn + t * 16 + l16) * 32 + quad * 8];
    }
#pragma unroll
    for (int mt = 0; mt < 4; ++mt)
#pragma unroll
      for (int nt = 0; nt < 4; ++nt)
        acc[mt][nt] = MFMA_BF16(af[mt], bfr[nt], acc[mt][nt]);
    // cvt + ds_write B(it+1) (f latency covered by the MFMAs above);
    // consumed before next barrier -> never outstanding across it
    if (it < 23) {
#pragma unroll
      for (int j = 0; j < 4; ++j) {
        bf16x4 pv;
        pv[0] = (__bf16)f[j].x; pv[1] = (__bf16)f[j].y;
        pv[2] = (__bf16)f[j].z; pv[3] = (__bf16)f[j].w;
        *(bf16x4*)&Bs[c ^ 1][(brow + 32 * j) * 32 + bcol] = pv;
      }
    }
  }

  // epilogue; z==0 pre-scales Q by 0.125*log2e (softmax scale fold)
  const float qs = (z == 0) ? 0.18033688011112042f : 1.0f;
#pragma unroll
  for (int mt = 0; mt < 4; ++mt) {
    const int e = m0 + wm + mt * 16 + quad * 4;
    const float4 b4 = *(const float4*)&bias[e];
    const int h = e >> 6, d = e & 63;
#pragma unroll
    for (int nt = 0; nt < 4; ++nt) {
      const int s = n0 + wn + nt * 16 + l16;
      const int bb = s >> 11, sr = s & 2047;
      const float v0 = (acc[mt][nt][0] + b4.x) * qs;
      const float v1 = (acc[mt][nt][1] + b4.y) * qs;
      const float v2 = (acc[mt][nt][2] + b4.z) * qs;
      const float v3 = (acc[mt][nt][3] + b4.w) * qs;
      if (z < 2) {
        bf16x4 pv;
        pv[0] = (__bf16)v0; pv[1] = (__bf16)v1; pv[2] = (__bf16)v2; pv[3] = (__bf16)v3;
        const int col = (z == 0) ? d : ((((d >> 3) ^ (sr & 7)) << 3) | (d & 7));
        *(bf16x4*)&Dst[((size_t)(bb * 12 + h) * 2048 + sr) * 64 + col] = pv;
      } else {
        const size_t rowbase = ((size_t)(bb * 12 + h) * 64 + d) * 2048;
        const int shi = sr & ~63, sblk = (sr >> 3) & 7, soff = sr & 7;
        Dst[rowbase + 0 * 2048 + shi + (((sblk ^ ((d + 0) & 7))) << 3) + soff] = (__bf16)v0;
        Dst[rowbase + 1 * 2048 + shi + (((sblk ^ ((d + 1) & 7))) << 3) + soff] = (__bf16)v1;
        Dst[rowbase + 2 * 2048 + shi + (((sblk ^ ((d + 2) & 7))) << 3) + soff] = (__bf16)v2;
        Dst[rowbase + 3 * 2048 + shi + (((sblk ^ ((d + 3) & 7))) << 3) + soff] = (__bf16)v3;
      }
    }
  }
}

// ---------------------------------------------------------------------------
// Output projection GEMM. grid (6, 64), block 256. All-glds, one barrier
// per K-tile (R5-exact). XCD swizzle cpx=48.
// ---------------------------------------------------------------------------
__global__ __launch_bounds__(256) void out_gemm(const __bf16* __restrict__ Wto,
                                                const __bf16* __restrict__ Ctx,
                                                const float* __restrict__ bo,
                                                float* __restrict__ Out) {
  __shared__ __align__(16) __bf16 As[2][128 * 32];
  __shared__ __align__(16) __bf16 Bs[2][128 * 32];
  const int gid = blockIdx.x + 6 * blockIdx.y;
  const int swz = (gid & 7) * 48 + (gid >> 3);
  const int by = swz / 6;
  const int bx = swz - by * 6;
  const int m0 = bx * 128, n0 = by * 128;
  const int tid = threadIdx.x, lane = tid & 63, w = tid >> 6;
  const int quad = lane >> 4, l16 = lane & 15;
  const int wm = (w >> 1) * 64, wn = (w & 1) * 64;

  const int grow = w * 32 + (lane >> 2);
  const int gcol = (lane & 3) * 8;
  const __bf16* gA = Wto + (size_t)(m0 + grow) * 768 + gcol;
  const __bf16* gB = Ctx + (size_t)(n0 + grow) * 768 + gcol;

  floatx4 acc[4][4] = {};

  // prologue: stage tile 0
  glds16(gA, &As[0][w * 1024]);
  glds16(gA + (size_t)16 * 768, &As[0][w * 1024 + 512]);
  glds16(gB, &Bs[0][w * 1024]);
  glds16(gB + (size_t)16 * 768, &Bs[0][w * 1024 + 512]);

#pragma unroll 2
  for (int it = 0; it < 24; ++it) {
    const int c = it & 1;
    __syncthreads();
    if (it < 23) {
      glds16(gA + (size_t)(it + 1) * 32, &As[c ^ 1][w * 1024]);
      glds16(gA + (size_t)(it + 1) * 32 + (size_t)16 * 768,
             &As[c ^ 1][w * 1024 + 512]);
      glds16(gB + (size_t)(it + 1) * 32, &Bs[c ^ 1][w * 1024]);
      glds16(gB + (size_t)(it + 1) * 32 + (size_t)16 * 768,
             &Bs[c ^ 1][w * 1024 + 512]);
    }
    bf16x8 af[4], bfr[4];
#pragma unroll
    for (int t = 0; t < 4; ++t) {
      af[t] = *(const bf16x8*)&As[c][(wm + t * 16 + l16) * 32 + quad * 8];
      bfr[t] = *(const bf16x8*)&Bs[c][(wn + t * 16 + l16) * 32 + quad * 8];
    }
#pragma unroll
    for (int mt = 0; mt < 4; ++mt)
#pragma unroll
      for (int nt = 0; nt < 4; ++nt)
        acc[mt][nt] = MFMA_BF16(af[mt], bfr[nt], acc[mt][nt]);
  }

#pragma unroll
  for (int mt = 0; mt < 4; ++mt) {
    const int e = m0 + wm + mt * 16 + quad * 4;
    const float4 b4 = *(const float4*)&bo[e];
#pragma unroll
    for (int nt = 0; nt < 4; ++nt) {
      const int s = n0 + wn + nt * 16 + l16;
      float4 r;
      r.x = acc[mt][nt][0] + b4.x;
      r.y = acc[mt][nt][1] + b4.y;
      r.z = acc[mt][nt][2] + b4.z;
      r.w = acc[mt][nt][3] + b4.w;
      *(float4*)&Out[(size_t)s * 768 + e] = r;
    }
  }
}

// ---------------------------------------------------------------------------
// Flash attention. grid (16, 48), block 256 (4 waves). Double-buffered K/V,
// one barrier/iter; bias in QK^T acc-init; exp2 direct; in-register P^T
// transpose; rS via ones-MFMA; setprio around MFMA clusters (T5).
// XCD swizzle: cpx=96; K/V panels L2-resident per XCD.
// ---------------------------------------------------------------------------
__global__ __launch_bounds__(256) void attn_kernel(
    const __bf16* __restrict__ Qh, const __bf16* __restrict__ Kh,
    const __bf16* __restrict__ Vt, const float* __restrict__ biasF,
    __bf16* __restrict__ ctx) {
  const int lid = blockIdx.x + 16 * blockIdx.y;
  const int swz = (lid & 7) * 96 + (lid >> 3);
  const int qx = swz & 15, bh = swz >> 4;
  const int b = bh / 12, h = bh - b * 12;
  const int tid = threadIdx.x, lane = tid & 63, w = tid >> 6;
  const int quad = lane >> 4, l16 = lane & 15;
  const int q0 = qx * 128 + w * 32;

  __shared__ __align__(16) __bf16 Ks[2][64 * 64];     // [buf][key][d-swz]
  __shared__ __align__(16) __bf16 Vs[2][64 * 64];     // [buf][d][key-swz]

  const __bf16* Qbase = Qh + (size_t)bh * 2048 * 64;
  const __bf16* Kbase = Kh + (size_t)bh * 2048 * 64;
  const __bf16* Vbase = Vt + (size_t)bh * 64 * 2048;
  const float* biasB = biasF + b * 2048;

  // Q B-frags (plain layout, pre-scaled): B[k=d][n=q] from Qh[q][d]
  bf16x8 bqf[2][2];
#pragma unroll
  for (int qt = 0; qt < 2; ++qt)
#pragma unroll
    for (int c = 0; c < 2; ++c)
      bqf[qt][c] =
          *(const bf16x8*)&Qbase[(size_t)(q0 + qt * 16 + l16) * 64 + c * 32 + quad * 8];

  // staging (128 B rows): chunk c covers rows c*8 + (lane>>3), col (lane&7)*8
  const int r0 = (w * 2) * 8 + (lane >> 3);
  const int r1 = (w * 2 + 1) * 8 + (lane >> 3);
  const int scol = (lane & 7) * 8;
  const int d0 = (w * 2) * 512;
  const int d1 = (w * 2 + 1) * 512;
  const int col0 = (quad ^ (l16 & 7)) * 8;

  // prologue: stage tile 0 into buffer 0
  glds16(&Kbase[(size_t)r0 * 64 + scol], &Ks[0][d0]);
  glds16(&Kbase[(size_t)r1 * 64 + scol], &Ks[0][d1]);
  glds16(&Vbase[(size_t)r0 * 2048 + scol], &Vs[0][d0]);
  glds16(&Vbase[(size_t)r1 * 2048 + scol], &Vs[0][d1]);

  floatx4 o[4][2] = {};   // O^T accs: [d-tile][q-tile]
  floatx4 os[2] = {};     // rS accs via ones-MFMA
  bf16x8 ones8;
#pragma unroll
  for (int j = 0; j < 8; ++j) ones8[j] = (__bf16)1.0f;

  for (int it = 0; it < 32; ++it) {
    const int kt = it * 64;
    const int cur = it & 1;
    const int nxt = cur ^ 1;
    const int nkt = (kt + 64) & 2047;  // wrap: last-iter prefetch is harmless

    __syncthreads();  // drains tile-`it` staging (in flight since iter it-1)

    // ---- prefetch tile it+1 into the other buffer (overlaps compute below)
    glds16(&Kbase[(size_t)(nkt + r0) * 64 + scol], &Ks[nxt][d0]);
    glds16(&Kbase[(size_t)(nkt + r1) * 64 + scol], &Ks[nxt][d1]);
    glds16(&Vbase[(size_t)r0 * 2048 + nkt + scol], &Vs[nxt][d0]);
    glds16(&Vbase[(size_t)r1 * 2048 + nkt + scol], &Vs[nxt][d1]);

    // ---- scores S^T with bias in acc-init: 4 key-tiles x 2 q-tiles
    floatx4 sc[4][2];
    __builtin_amdgcn_s_setprio(1);
#pragma unroll
    for (int t = 0; t < 4; ++t) {
      const float4 bf4 = *(const float4*)&biasB[kt + t * 16 + quad * 4];
      bf16x8 ak0 = *(const bf16x8*)&Ks[cur][(t * 16 + l16) * 64 + col0];
      bf16x8 ak1 = *(const bf16x8*)&Ks[cur][(t * 16 + l16) * 64 + (col0 ^ 32)];
#pragma unroll
      for (int qt = 0; qt < 2; ++qt) {
        floatx4 zz;
        zz[0] = bf4.x; zz[1] = bf4.y; zz[2] = bf4.z; zz[3] = bf4.w;
        zz = MFMA_BF16(ak0, bqf[qt][0], zz);
        zz = MFMA_BF16(ak1, bqf[qt][1], zz);
        sc[t][qt] = zz;
      }
    }
    __builtin_amdgcn_s_setprio(0);
    // ---- p = exp2(s); pack pairs to bf16 words (keys +0,1 / +2,3 per word)
    unsigned int u[4][2][2];
#pragma unroll
    for (int t = 0; t < 4; ++t)
#pragma unroll
      for (int qt = 0; qt < 2; ++qt) {
        const float e0 = __builtin_amdgcn_exp2f(sc[t][qt][0]);
        const float e1 = __builtin_amdgcn_exp2f(sc[t][qt][1]);
        const float e2 = __builtin_amdgcn_exp2f(sc[t][qt][2]);
        const float e3 = __builtin_amdgcn_exp2f(sc[t][qt][3]);
        asm("v_cvt_pk_bf16_f32 %0, %1, %2" : "=v"(u[t][qt][0]) : "v"(e0), "v"(e1));
        asm("v_cvt_pk_bf16_f32 %0, %1, %2" : "=v"(u[t][qt][1]) : "v"(e2), "v"(e3));
      }
    // ---- in-register P^T -> B-frags; O^T += V^T @ P^T; rS += ones @ P^T
#pragma unroll
    for (int c = 0; c < 2; ++c) {
      bf16x8 bp[2];
#pragma unroll
      for (int qt = 0; qt < 2; ++qt) {
        unsigned int w0 = u[2 * c][qt][0], w1 = u[2 * c][qt][1];
        unsigned int w2 = u[2 * c + 1][qt][0], w3 = u[2 * c + 1][qt][1];
        perm32_swap(w0, w2);
        perm32_swap(w1, w3);
        perm16_swap(w0, w2);
        perm16_swap(w1, w3);
        union { unsigned int wd[4]; bf16x8 v; } ub;
        ub.wd[0] = w0; ub.wd[1] = w1; ub.wd[2] = w2; ub.wd[3] = w3;
        bp[qt] = ub.v;
      }
      __builtin_amdgcn_s_setprio(1);
      os[0] = MFMA_BF16(ones8, bp[0], os[0]);
      os[1] = MFMA_BF16(ones8, bp[1], os[1]);
#pragma unroll
      for (int dt = 0; dt < 4; ++dt) {
        bf16x8 av = *(const bf16x8*)&Vs[cur][(dt * 16 + l16) * 64 + (col0 ^ (c * 32))];
#pragma unroll
        for (int qt = 0; qt < 2; ++qt) o[dt][qt] = MFMA_BF16(av, bp[qt], o[dt][qt]);
      }
      __builtin_amdgcn_s_setprio(0);
    }
  }

  // ---- normalize + write ctx (every lane holds its q's sum in os[qt][0])
  float inv[2];
  inv[0] = 1.0f / os[0][0];
  inv[1] = 1.0f / os[1][0];
#pragma unroll
  for (int dt = 0; dt < 4; ++dt)
#pragma unroll
    for (int qt = 0; qt < 2; ++qt) {
      const int q = q0 + qt * 16 + l16;
      const int d = h * 64 + dt * 16 + quad * 4;
      bf16x4 pv;
      pv[0] = (__bf16)(o[dt][qt][0] * inv[qt]);
      pv[1] = (__bf16)(o[dt][qt][1] * inv[qt]);
      pv[2] = (__bf16)(o[dt][qt][2] * inv[qt]);
      pv[3] = (__bf16)(o[dt][qt][3] * inv[qt]);
      *(bf16x4*)&ctx[(size_t)(b * 2048 + q) * 768 + d] = pv;
    }
}

// ---------------------------------------------------------------------------
extern "C" void kernel_launch(void* const* d_in, const int* in_sizes, int n_in,
                              void* d_out, int out_size, void* d_ws, size_t ws_size,
                              hipStream_t stream) {
  const float* q = (const float*)d_in[0];
  const float* k = (const float*)d_in[1];
  const float* v = (const float*)d_in[2];
  const int* mask = (const int*)d_in[3];
  const float* Wq = (const float*)d_in[4];
  const float* bq = (const float*)d_in[5];
  const float* Wk = (const float*)d_in[6];
  const float* bk = (const float*)d_in[7];
  const float* Wv = (const float*)d_in[8];
  const float* bv = (const float*)d_in[9];
  const float* Wo = (const float*)d_in[10];
  const float* bo = (const float*)d_in[11];
  float* out = (float*)d_out;

  char* ws = (char*)d_ws;
  const size_t SZ = (size_t)8192 * 768 * 2;   // 12.58 MB
  const size_t WSZ = (size_t)768 * 768 * 2;   // 1.18 MB
  __bf16* Qh = (__bf16*)(ws);
  __bf16* Kh = (__bf16*)(ws + SZ);
  __bf16* Vt = (__bf16*)(ws + 2 * SZ);
  __bf16* ctx = (__bf16*)(ws + 3 * SZ);
  __bf16* Wtq = (__bf16*)(ws + 4 * SZ);
  __bf16* Wtk = (__bf16*)(ws + 4 * SZ + WSZ);
  __bf16* Wtv = (__bf16*)(ws + 4 * SZ + 2 * WSZ);
  __bf16* Wto = (__bf16*)(ws + 4 * SZ + 3 * WSZ);
  float* biasF = (float*)(ws + 4 * SZ + 4 * WSZ);  // 4*2048 f32 = 32 KB

  prep_transpose<<<dim3(24, 24, 4), 256, 0, stream>>>(Wq, Wk, Wv, Wo, Wtq, Wtk,
                                                      Wtv, Wto, mask, biasF);
  qkv_gemm<<<dim3(6, 64, 3), 256, 0, stream>>>(Wtq, Wtk, Wtv, q, k, v, bq, bk, bv,
                                               Qh, Kh, Vt);
  attn_kernel<<<dim3(16, 48), 256, 0, stream>>>(Qh, Kh, Vt, biasF, ctx);
  out_gemm<<<dim3(6, 64), 256, 0, stream>>>(Wto, ctx, bo, out);
}

// Round 8
// 280.078 us; speedup vs baseline: 1.1821x; 1.1248x over previous
//
#include <hip/hip_runtime.h>
#include <hip/hip_bf16.h>
#include <stdint.h>

// MultiHeadAttention fused pipeline for MI355X (gfx950).
// B=4, S=2048, E=768, H=12, D=64.
//  prep_fused: z<4: W fp32 -> Wt bf16 (transpose) + mask->biasF;
//     z>=4: X fp32 -> bf16 streaming convert (9216 blocks, 2048 f32 each).
//  qkv_gemm (z): C[m=e][n=s] = Wt x Xb^T, BOTH operands glds16-staged,
//     ONE barrier per K-tile (prefetch issued right after the barrier ->
//     full-iter slack before its drain at the next barrier). R5-exact.
//     Epilogue: z=0 Qh plain [BH][S][64] PRE-SCALED by 0.125*log2e;
//     z=1 Kh d-block XOR-swizzled by s&7; z=2 Vt [BH][64][S], key-block
//     XOR-swizzled by d&7 per 64-key window.
//  attn: R5-exact (76.5 us measured): double-buffered K/V, one barrier,
//     bias in MFMA acc-init, exp2 direct, in-register P^T transpose,
//     rS via ones-MFMA. NO setprio (lockstep 4-wave = m190 regime;
//     R7's +14us unexplained regression attributed to it).
//  out_gemm: R5-exact one-barrier all-glds loop.
//
// Evidence ledger:
// R1: XCD swizzle -> attn FETCH 107.7->18.5 MB (L2-resident).
// R2/R3: attn in-reg P^T + bias-in-acc + ones-MFMA rS: 99 -> 76.5 us,
//   attn bank conflicts 4.7M -> 0.
// R4/R7: reg-staged B fails at ANY schedule (101/106 vs 86.5 two-barrier;
//   same-iter consume still forces vmcnt(0) mid-iter: f issued after
//   glds-A -> cvt wait drains A with zero slack).
// R5: all-glds one-barrier qkv is the fastest qkv (<76 us); xcvt pass
//   (~18us + launch) ate the win. Total 285.1.
// R6: fp32-B-in-LDS 122us (48KB LDS, 2x staging bytes). qkv bank-conflict
//   counter (3538944) bit-identical under every frag-read swizzle -> inert.
// R8: fuse xcvt into prep (one fewer launch/drain); revert attn to R5;
//   qkv/out R5-exact.

typedef __bf16 bf16x8 __attribute__((ext_vector_type(8)));
typedef __bf16 bf16x4 __attribute__((ext_vector_type(4)));
typedef float floatx4 __attribute__((ext_vector_type(4)));

#define MFMA_BF16(a, b, c) __builtin_amdgcn_mfma_f32_16x16x32_bf16(a, b, c, 0, 0, 0)

// MFMA 16x16x32 layouts (verified, learn_hip m89/m91):
//   A frag: A[m = lane&15][k = (lane>>4)*8 + j]
//   B frag: B[k = (lane>>4)*8 + j][n = lane&15]   (read from [n][k] storage)
//   C/D  : C[m = (lane>>4)*4 + r][n = lane&15]

__device__ __forceinline__ void glds16(const void* g, void* l) {
  __builtin_amdgcn_global_load_lds(
      (const __attribute__((address_space(1))) unsigned int*)g,
      (__attribute__((address_space(3))) unsigned int*)l, 16, 0, 0);
}

#if __has_builtin(__builtin_amdgcn_permlane32_swap)
__device__ __forceinline__ void perm32_swap(unsigned int& a, unsigned int& b) {
  auto r = __builtin_amdgcn_permlane32_swap(a, b, false, false);
  a = r[0];
  b = r[1];
}
#else
__device__ __forceinline__ void perm32_swap(unsigned int& a, unsigned int& b) {
  asm("v_permlane32_swap_b32 %0, %1" : "+v"(a), "+v"(b));
}
#endif

#if __has_builtin(__builtin_amdgcn_permlane16_swap)
__device__ __forceinline__ void perm16_swap(unsigned int& a, unsigned int& b) {
  auto r = __builtin_amdgcn_permlane16_swap(a, b, false, false);
  a = r[0];
  b = r[1];
}
#else
__device__ __forceinline__ void perm16_swap(unsigned int& a, unsigned int& b) {
  asm("v_permlane16_swap_b32 %0, %1" : "+v"(a), "+v"(b));
}
#endif

// ---------------------------------------------------------------------------
// prep_fused. grid (24, 24, 20), block 256.
//  z<4 : weight transpose (LDS 32x33) + (z==3,by==0,bx<8) mask->biasF.
//  z>=4: X fp32->bf16 convert; chunk = (z-4)*576 + by*24 + bx (9216 chunks,
//        3072/tensor, 2048 f32 each = 8/thread).
// ---------------------------------------------------------------------------
__global__ __launch_bounds__(256) void prep_fused(
    const float* __restrict__ W0, const float* __restrict__ W1,
    const float* __restrict__ W2, const float* __restrict__ W3,
    __bf16* __restrict__ T0, __bf16* __restrict__ T1,
    __bf16* __restrict__ T2, __bf16* __restrict__ T3,
    const int* __restrict__ mask, float* __restrict__ biasF,
    const float* __restrict__ X0, const float* __restrict__ X1,
    const float* __restrict__ X2, __bf16* __restrict__ Y0,
    __bf16* __restrict__ Y1, __bf16* __restrict__ Y2) {
  const int z = blockIdx.z;
  if (z >= 4) {
    const int chunk = (z - 4) * 576 + blockIdx.y * 24 + blockIdx.x;
    const int t = chunk / 3072;  // 3072 chunks per tensor
    const float* X = (t == 0) ? X0 : (t == 1) ? X1 : X2;
    __bf16* Y = (t == 0) ? Y0 : (t == 1) ? Y1 : Y2;
    const size_t i = (size_t)(chunk - t * 3072) * 2048 + threadIdx.x * 8;
    const float4 a = *(const float4*)&X[i];
    const float4 b = *(const float4*)&X[i + 4];
    bf16x4 p0, p1;
    p0[0] = (__bf16)a.x; p0[1] = (__bf16)a.y;
    p0[2] = (__bf16)a.z; p0[3] = (__bf16)a.w;
    p1[0] = (__bf16)b.x; p1[1] = (__bf16)b.y;
    p1[2] = (__bf16)b.z; p1[3] = (__bf16)b.w;
    *(bf16x4*)&Y[i] = p0;
    *(bf16x4*)&Y[i + 4] = p1;
    return;
  }
  const float* W = (z == 0) ? W0 : (z == 1) ? W1 : (z == 2) ? W2 : W3;
  __bf16* T = (z == 0) ? T0 : (z == 1) ? T1 : (z == 2) ? T2 : T3;
  __shared__ float t[32][33];
  const int tx = threadIdx.x & 31, ty = threadIdx.x >> 5;
  const int kb = blockIdx.x * 32, nb = blockIdx.y * 32;
#pragma unroll
  for (int j = 0; j < 4; ++j)
    t[ty + j * 8][tx] = W[(size_t)(kb + ty + j * 8) * 768 + nb + tx];
  if (z == 3 && blockIdx.y == 0 && blockIdx.x < 8) {
    const int idx = blockIdx.x * 1024 + threadIdx.x * 4;
    const int4 m4 = *(const int4*)&mask[idx];
    float4 f4;
    f4.x = m4.x ? 0.0f : -1e5f;
    f4.y = m4.y ? 0.0f : -1e5f;
    f4.z = m4.z ? 0.0f : -1e5f;
    f4.w = m4.w ? 0.0f : -1e5f;
    *(float4*)&biasF[idx] = f4;
  }
  __syncthreads();
#pragma unroll
  for (int j = 0; j < 4; ++j)
    T[(size_t)(nb + ty + j * 8) * 768 + kb + tx] = (__bf16)t[tx][ty + j * 8];
}

// ---------------------------------------------------------------------------
// QKV projection GEMM. grid (6, 64, 3), block 256. Tile 128x128, BK=32.
// All-glds staging, ONE barrier per K-tile (R5-exact). XCD swizzle cpx=144.
// ---------------------------------------------------------------------------
__global__ __launch_bounds__(256) void qkv_gemm(
    const __bf16* __restrict__ Wtq, const __bf16* __restrict__ Wtk,
    const __bf16* __restrict__ Wtv, const __bf16* __restrict__ Xbq,
    const __bf16* __restrict__ Xbk, const __bf16* __restrict__ Xbv,
    const float* __restrict__ bq, const float* __restrict__ bk,
    const float* __restrict__ bv, __bf16* __restrict__ Qh,
    __bf16* __restrict__ Kh, __bf16* __restrict__ Vt) {
  __shared__ __align__(16) __bf16 As[2][128 * 32];
  __shared__ __align__(16) __bf16 Bs[2][128 * 32];
  const int gid = blockIdx.x + 6 * blockIdx.y + 384 * blockIdx.z;
  const int swz = (gid & 7) * 144 + (gid >> 3);
  const int z = swz / 384;
  const int rem = swz - z * 384;
  const int by = rem / 6;
  const int bx = rem - by * 6;

  const __bf16* Aop = (z == 0) ? Wtq : (z == 1) ? Wtk : Wtv;
  const __bf16* Bop = (z == 0) ? Xbq : (z == 1) ? Xbk : Xbv;
  const float* bias = (z == 0) ? bq : (z == 1) ? bk : bv;
  __bf16* Dst = (z == 0) ? Qh : (z == 1) ? Kh : Vt;
  const int m0 = bx * 128, n0 = by * 128;

  const int tid = threadIdx.x, lane = tid & 63, w = tid >> 6;
  const int quad = lane >> 4, l16 = lane & 15;
  const int wm = (w >> 1) * 64, wn = (w & 1) * 64;

  // staging (64 B rows): wave w insts j=0,1 -> rows w*32 + j*16 + (lane>>2)
  const int grow = w * 32 + (lane >> 2);
  const int gcol = (lane & 3) * 8;
  const __bf16* gA = Aop + (size_t)(m0 + grow) * 768 + gcol;  // tile j: +j*32
  const __bf16* gB = Bop + (size_t)(n0 + grow) * 768 + gcol;  // tile j: +j*32

  floatx4 acc[4][4] = {};

  // prologue: stage tile 0 (drained at the loop's first barrier)
  glds16(gA, &As[0][w * 1024]);
  glds16(gA + (size_t)16 * 768, &As[0][w * 1024 + 512]);
  glds16(gB, &Bs[0][w * 1024]);
  glds16(gB + (size_t)16 * 768, &Bs[0][w * 1024 + 512]);

#pragma unroll 2
  for (int it = 0; it < 24; ++it) {
    const int c = it & 1;
    __syncthreads();  // drains tile-it staging (issued a full iter ago)
    // prefetch tile it+1 into the other buffer (read in it-1; all its
    // readers passed this barrier -> safe)
    if (it < 23) {
      glds16(gA + (size_t)(it + 1) * 32, &As[c ^ 1][w * 1024]);
      glds16(gA + (size_t)(it + 1) * 32 + (size_t)16 * 768,
             &As[c ^ 1][w * 1024 + 512]);
      glds16(gB + (size_t)(it + 1) * 32, &Bs[c ^ 1][w * 1024]);
      glds16(gB + (size_t)(it + 1) * 32 + (size_t)16 * 768,
             &Bs[c ^ 1][w * 1024 + 512]);
    }
    bf16x8 af[4], bfr[4];
#pragma unroll
    for (int t = 0; t < 4; ++t) {
      af[t] = *(const bf16x8*)&As[c][(wm + t * 16 + l16) * 32 + quad * 8];
      bfr[t] = *(const bf16x8*)&Bs[c][(wn + t * 16 + l16) * 32 + quad * 8];
    }
#pragma unroll
    for (int mt = 0; mt < 4; ++mt)
#pragma unroll
      for (int nt = 0; nt < 4; ++nt)
        acc[mt][nt] = MFMA_BF16(af[mt], bfr[nt], acc[mt][nt]);
  }

  // epilogue; z==0 pre-scales Q by 0.125*log2e (softmax scale fold)
  const float qs = (z == 0) ? 0.18033688011112042f : 1.0f;
#pragma unroll
  for (int mt = 0; mt < 4; ++mt) {
    const int e = m0 + wm + mt * 16 + quad * 4;
    const float4 b4 = *(const float4*)&bias[e];
    const int h = e >> 6, d = e & 63;
#pragma unroll
    for (int nt = 0; nt < 4; ++nt) {
      const int s = n0 + wn + nt * 16 + l16;
      const int bb = s >> 11, sr = s & 2047;
      const float v0 = (acc[mt][nt][0] + b4.x) * qs;
      const float v1 = (acc[mt][nt][1] + b4.y) * qs;
      const float v2 = (acc[mt][nt][2] + b4.z) * qs;
      const float v3 = (acc[mt][nt][3] + b4.w) * qs;
      if (z < 2) {
        bf16x4 pv;
        pv[0] = (__bf16)v0; pv[1] = (__bf16)v1; pv[2] = (__bf16)v2; pv[3] = (__bf16)v3;
        const int col = (z == 0) ? d : ((((d >> 3) ^ (sr & 7)) << 3) | (d & 7));
        *(bf16x4*)&Dst[((size_t)(bb * 12 + h) * 2048 + sr) * 64 + col] = pv;
      } else {
        const size_t rowbase = ((size_t)(bb * 12 + h) * 64 + d) * 2048;
        const int shi = sr & ~63, sblk = (sr >> 3) & 7, soff = sr & 7;
        Dst[rowbase + 0 * 2048 + shi + (((sblk ^ ((d + 0) & 7))) << 3) + soff] = (__bf16)v0;
        Dst[rowbase + 1 * 2048 + shi + (((sblk ^ ((d + 1) & 7))) << 3) + soff] = (__bf16)v1;
        Dst[rowbase + 2 * 2048 + shi + (((sblk ^ ((d + 2) & 7))) << 3) + soff] = (__bf16)v2;
        Dst[rowbase + 3 * 2048 + shi + (((sblk ^ ((d + 3) & 7))) << 3) + soff] = (__bf16)v3;
      }
    }
  }
}

// ---------------------------------------------------------------------------
// Output projection GEMM. grid (6, 64), block 256. All-glds, one barrier
// per K-tile (R5-exact). XCD swizzle cpx=48.
// ---------------------------------------------------------------------------
__global__ __launch_bounds__(256) void out_gemm(const __bf16* __restrict__ Wto,
                                                const __bf16* __restrict__ Ctx,
                                                const float* __restrict__ bo,
                                                float* __restrict__ Out) {
  __shared__ __align__(16) __bf16 As[2][128 * 32];
  __shared__ __align__(16) __bf16 Bs[2][128 * 32];
  const int gid = blockIdx.x + 6 * blockIdx.y;
  const int swz = (gid & 7) * 48 + (gid >> 3);
  const int by = swz / 6;
  const int bx = swz - by * 6;
  const int m0 = bx * 128, n0 = by * 128;
  const int tid = threadIdx.x, lane = tid & 63, w = tid >> 6;
  const int quad = lane >> 4, l16 = lane & 15;
  const int wm = (w >> 1) * 64, wn = (w & 1) * 64;

  const int grow = w * 32 + (lane >> 2);
  const int gcol = (lane & 3) * 8;
  const __bf16* gA = Wto + (size_t)(m0 + grow) * 768 + gcol;
  const __bf16* gB = Ctx + (size_t)(n0 + grow) * 768 + gcol;

  floatx4 acc[4][4] = {};

  // prologue: stage tile 0
  glds16(gA, &As[0][w * 1024]);
  glds16(gA + (size_t)16 * 768, &As[0][w * 1024 + 512]);
  glds16(gB, &Bs[0][w * 1024]);
  glds16(gB + (size_t)16 * 768, &Bs[0][w * 1024 + 512]);

#pragma unroll 2
  for (int it = 0; it < 24; ++it) {
    const int c = it & 1;
    __syncthreads();
    if (it < 23) {
      glds16(gA + (size_t)(it + 1) * 32, &As[c ^ 1][w * 1024]);
      glds16(gA + (size_t)(it + 1) * 32 + (size_t)16 * 768,
             &As[c ^ 1][w * 1024 + 512]);
      glds16(gB + (size_t)(it + 1) * 32, &Bs[c ^ 1][w * 1024]);
      glds16(gB + (size_t)(it + 1) * 32 + (size_t)16 * 768,
             &Bs[c ^ 1][w * 1024 + 512]);
    }
    bf16x8 af[4], bfr[4];
#pragma unroll
    for (int t = 0; t < 4; ++t) {
      af[t] = *(const bf16x8*)&As[c][(wm + t * 16 + l16) * 32 + quad * 8];
      bfr[t] = *(const bf16x8*)&Bs[c][(wn + t * 16 + l16) * 32 + quad * 8];
    }
#pragma unroll
    for (int mt = 0; mt < 4; ++mt)
#pragma unroll
      for (int nt = 0; nt < 4; ++nt)
        acc[mt][nt] = MFMA_BF16(af[mt], bfr[nt], acc[mt][nt]);
  }

#pragma unroll
  for (int mt = 0; mt < 4; ++mt) {
    const int e = m0 + wm + mt * 16 + quad * 4;
    const float4 b4 = *(const float4*)&bo[e];
#pragma unroll
    for (int nt = 0; nt < 4; ++nt) {
      const int s = n0 + wn + nt * 16 + l16;
      float4 r;
      r.x = acc[mt][nt][0] + b4.x;
      r.y = acc[mt][nt][1] + b4.y;
      r.z = acc[mt][nt][2] + b4.z;
      r.w = acc[mt][nt][3] + b4.w;
      *(float4*)&Out[(size_t)s * 768 + e] = r;
    }
  }
}

// ---------------------------------------------------------------------------
// Flash attention. grid (16, 48), block 256 (4 waves). R5-exact (76.5 us):
// double-buffered K/V, one barrier/iter; bias in QK^T acc-init; exp2
// direct; in-register P^T transpose; rS via ones-MFMA. No setprio.
// XCD swizzle: cpx=96; K/V panels L2-resident per XCD.
// ---------------------------------------------------------------------------
__global__ __launch_bounds__(256) void attn_kernel(
    const __bf16* __restrict__ Qh, const __bf16* __restrict__ Kh,
    const __bf16* __restrict__ Vt, const float* __restrict__ biasF,
    __bf16* __restrict__ ctx) {
  const int lid = blockIdx.x + 16 * blockIdx.y;
  const int swz = (lid & 7) * 96 + (lid >> 3);
  const int qx = swz & 15, bh = swz >> 4;
  const int b = bh / 12, h = bh - b * 12;
  const int tid = threadIdx.x, lane = tid & 63, w = tid >> 6;
  const int quad = lane >> 4, l16 = lane & 15;
  const int q0 = qx * 128 + w * 32;

  __shared__ __align__(16) __bf16 Ks[2][64 * 64];     // [buf][key][d-swz]
  __shared__ __align__(16) __bf16 Vs[2][64 * 64];     // [buf][d][key-swz]

  const __bf16* Qbase = Qh + (size_t)bh * 2048 * 64;
  const __bf16* Kbase = Kh + (size_t)bh * 2048 * 64;
  const __bf16* Vbase = Vt + (size_t)bh * 64 * 2048;
  const float* biasB = biasF + b * 2048;

  // Q B-frags (plain layout, pre-scaled): B[k=d][n=q] from Qh[q][d]
  bf16x8 bqf[2][2];
#pragma unroll
  for (int qt = 0; qt < 2; ++qt)
#pragma unroll
    for (int c = 0; c < 2; ++c)
      bqf[qt][c] =
          *(const bf16x8*)&Qbase[(size_t)(q0 + qt * 16 + l16) * 64 + c * 32 + quad * 8];

  // staging (128 B rows): chunk c covers rows c*8 + (lane>>3), col (lane&7)*8
  const int r0 = (w * 2) * 8 + (lane >> 3);
  const int r1 = (w * 2 + 1) * 8 + (lane >> 3);
  const int scol = (lane & 7) * 8;
  const int d0 = (w * 2) * 512;
  const int d1 = (w * 2 + 1) * 512;
  const int col0 = (quad ^ (l16 & 7)) * 8;

  // prologue: stage tile 0 into buffer 0
  glds16(&Kbase[(size_t)r0 * 64 + scol], &Ks[0][d0]);
  glds16(&Kbase[(size_t)r1 * 64 + scol], &Ks[0][d1]);
  glds16(&Vbase[(size_t)r0 * 2048 + scol], &Vs[0][d0]);
  glds16(&Vbase[(size_t)r1 * 2048 + scol], &Vs[0][d1]);

  floatx4 o[4][2] = {};   // O^T accs: [d-tile][q-tile]
  floatx4 os[2] = {};     // rS accs via ones-MFMA
  bf16x8 ones8;
#pragma unroll
  for (int j = 0; j < 8; ++j) ones8[j] = (__bf16)1.0f;

  for (int it = 0; it < 32; ++it) {
    const int kt = it * 64;
    const int cur = it & 1;
    const int nxt = cur ^ 1;
    const int nkt = (kt + 64) & 2047;  // wrap: last-iter prefetch is harmless

    __syncthreads();  // drains tile-`it` staging (in flight since iter it-1)

    // ---- prefetch tile it+1 into the other buffer (overlaps compute below)
    glds16(&Kbase[(size_t)(nkt + r0) * 64 + scol], &Ks[nxt][d0]);
    glds16(&Kbase[(size_t)(nkt + r1) * 64 + scol], &Ks[nxt][d1]);
    glds16(&Vbase[(size_t)r0 * 2048 + nkt + scol], &Vs[nxt][d0]);
    glds16(&Vbase[(size_t)r1 * 2048 + nkt + scol], &Vs[nxt][d1]);

    // ---- scores S^T with bias in acc-init: 4 key-tiles x 2 q-tiles
    floatx4 sc[4][2];
#pragma unroll
    for (int t = 0; t < 4; ++t) {
      const float4 bf4 = *(const float4*)&biasB[kt + t * 16 + quad * 4];
      bf16x8 ak0 = *(const bf16x8*)&Ks[cur][(t * 16 + l16) * 64 + col0];
      bf16x8 ak1 = *(const bf16x8*)&Ks[cur][(t * 16 + l16) * 64 + (col0 ^ 32)];
#pragma unroll
      for (int qt = 0; qt < 2; ++qt) {
        floatx4 zz;
        zz[0] = bf4.x; zz[1] = bf4.y; zz[2] = bf4.z; zz[3] = bf4.w;
        zz = MFMA_BF16(ak0, bqf[qt][0], zz);
        zz = MFMA_BF16(ak1, bqf[qt][1], zz);
        sc[t][qt] = zz;
      }
    }
    // ---- p = exp2(s); pack pairs to bf16 words (keys +0,1 / +2,3 per word)
    unsigned int u[4][2][2];
#pragma unroll
    for (int t = 0; t < 4; ++t)
#pragma unroll
      for (int qt = 0; qt < 2; ++qt) {
        const float e0 = __builtin_amdgcn_exp2f(sc[t][qt][0]);
        const float e1 = __builtin_amdgcn_exp2f(sc[t][qt][1]);
        const float e2 = __builtin_amdgcn_exp2f(sc[t][qt][2]);
        const float e3 = __builtin_amdgcn_exp2f(sc[t][qt][3]);
        asm("v_cvt_pk_bf16_f32 %0, %1, %2" : "=v"(u[t][qt][0]) : "v"(e0), "v"(e1));
        asm("v_cvt_pk_bf16_f32 %0, %1, %2" : "=v"(u[t][qt][1]) : "v"(e2), "v"(e3));
      }
    // ---- in-register P^T -> B-frags; O^T += V^T @ P^T; rS += ones @ P^T
#pragma unroll
    for (int c = 0; c < 2; ++c) {
      bf16x8 bp[2];
#pragma unroll
      for (int qt = 0; qt < 2; ++qt) {
        unsigned int w0 = u[2 * c][qt][0], w1 = u[2 * c][qt][1];
        unsigned int w2 = u[2 * c + 1][qt][0], w3 = u[2 * c + 1][qt][1];
        perm32_swap(w0, w2);
        perm32_swap(w1, w3);
        perm16_swap(w0, w2);
        perm16_swap(w1, w3);
        union { unsigned int wd[4]; bf16x8 v; } ub;
        ub.wd[0] = w0; ub.wd[1] = w1; ub.wd[2] = w2; ub.wd[3] = w3;
        bp[qt] = ub.v;
        os[qt] = MFMA_BF16(ones8, bp[qt], os[qt]);
      }
#pragma unroll
      for (int dt = 0; dt < 4; ++dt) {
        bf16x8 av = *(const bf16x8*)&Vs[cur][(dt * 16 + l16) * 64 + (col0 ^ (c * 32))];
#pragma unroll
        for (int qt = 0; qt < 2; ++qt) o[dt][qt] = MFMA_BF16(av, bp[qt], o[dt][qt]);
      }
    }
  }

  // ---- normalize + write ctx (every lane holds its q's sum in os[qt][0])
  float inv[2];
  inv[0] = 1.0f / os[0][0];
  inv[1] = 1.0f / os[1][0];
#pragma unroll
  for (int dt = 0; dt < 4; ++dt)
#pragma unroll
    for (int qt = 0; qt < 2; ++qt) {
      const int q = q0 + qt * 16 + l16;
      const int d = h * 64 + dt * 16 + quad * 4;
      bf16x4 pv;
      pv[0] = (__bf16)(o[dt][qt][0] * inv[qt]);
      pv[1] = (__bf16)(o[dt][qt][1] * inv[qt]);
      pv[2] = (__bf16)(o[dt][qt][2] * inv[qt]);
      pv[3] = (__bf16)(o[dt][qt][3] * inv[qt]);
      *(bf16x4*)&ctx[(size_t)(b * 2048 + q) * 768 + d] = pv;
    }
}

// ---------------------------------------------------------------------------
extern "C" void kernel_launch(void* const* d_in, const int* in_sizes, int n_in,
                              void* d_out, int out_size, void* d_ws, size_t ws_size,
                              hipStream_t stream) {
  const float* q = (const float*)d_in[0];
  const float* k = (const float*)d_in[1];
  const float* v = (const float*)d_in[2];
  const int* mask = (const int*)d_in[3];
  const float* Wq = (const float*)d_in[4];
  const float* bq = (const float*)d_in[5];
  const float* Wk = (const float*)d_in[6];
  const float* bk = (const float*)d_in[7];
  const float* Wv = (const float*)d_in[8];
  const float* bv = (const float*)d_in[9];
  const float* Wo = (const float*)d_in[10];
  const float* bo = (const float*)d_in[11];
  float* out = (float*)d_out;

  char* ws = (char*)d_ws;
  const size_t SZ = (size_t)8192 * 768 * 2;   // 12.58 MB
  const size_t WSZ = (size_t)768 * 768 * 2;   // 1.18 MB
  __bf16* Qh = (__bf16*)(ws);
  __bf16* Kh = (__bf16*)(ws + SZ);
  __bf16* Vt = (__bf16*)(ws + 2 * SZ);
  __bf16* ctx = (__bf16*)(ws + 3 * SZ);       // doubles as Xbq (dead post-qkv)
  __bf16* Xbq = ctx;
  __bf16* Xbk = (__bf16*)(ws + 4 * SZ);
  __bf16* Xbv = (__bf16*)(ws + 5 * SZ);
  __bf16* Wtq = (__bf16*)(ws + 6 * SZ);
  __bf16* Wtk = (__bf16*)(ws + 6 * SZ + WSZ);
  __bf16* Wtv = (__bf16*)(ws + 6 * SZ + 2 * WSZ);
  __bf16* Wto = (__bf16*)(ws + 6 * SZ + 3 * WSZ);
  float* biasF = (float*)(ws + 6 * SZ + 4 * WSZ);  // 4*2048 f32 = 32 KB

  prep_fused<<<dim3(24, 24, 20), 256, 0, stream>>>(Wq, Wk, Wv, Wo, Wtq, Wtk,
                                                   Wtv, Wto, mask, biasF,
                                                   q, k, v, Xbq, Xbk, Xbv);
  qkv_gemm<<<dim3(6, 64, 3), 256, 0, stream>>>(Wtq, Wtk, Wtv, Xbq, Xbk, Xbv,
                                               bq, bk, bv, Qh, Kh, Vt);
  attn_kernel<<<dim3(16, 48), 256, 0, stream>>>(Qh, Kh, Vt, biasF, ctx);
  out_gemm<<<dim3(6, 64), 256, 0, stream>>>(Wto, ctx, bo, out);
}